// Round 6
// baseline (240.711 us; speedup 1.0000x reference)
//
#include <hip/hip_runtime.h>
#include <stdint.h>

// Problem constants (reference file)
#define B_SZ 16
#define L_SZ 1024
#define D_SZ 512
#define E_SZ 8
#define DFF_SZ 2048

typedef short bf16x8 __attribute__((ext_vector_type(8)));
typedef float f32x4 __attribute__((ext_vector_type(4)));

__device__ __forceinline__ unsigned short f2bf(float f) {
  unsigned int u = __float_as_uint(f);
  u += 0x7fffu + ((u >> 16) & 1u);   // round-to-nearest-even
  return (unsigned short)(u >> 16);
}

__device__ __forceinline__ void async_cp16(void* lds, const void* g) {
  __builtin_amdgcn_global_load_lds(
      (const __attribute__((address_space(1))) void*)g,
      (__attribute__((address_space(3))) void*)lds, 16, 0, 0);
}

// ---------------------------------------------------------------------------
// Fused prep kernel (one dispatch): cast x + transpose W1,W2 + router.
// ---------------------------------------------------------------------------
__device__ __forceinline__ void transpose_body(const float* __restrict__ src,
                                               unsigned short* __restrict__ dst,
                                               int K, int N, int bx, int by,
                                               int bz, float (*tile)[65]) {
  const int n0 = bx * 64;
  const int k0 = by * 64;
  const int t = threadIdx.x;          // 256
  {
    const int c4 = (t & 15) * 4;
    const int r = t >> 4;
    const float* s = src + ((size_t)bz * K + k0) * N + n0;
#pragma unroll
    for (int i = 0; i < 4; ++i) {
      const int k = r + i * 16;
      const float4 v = *(const float4*)(s + (size_t)k * N + c4);
      tile[k][c4] = v.x; tile[k][c4 + 1] = v.y;
      tile[k][c4 + 2] = v.z; tile[k][c4 + 3] = v.w;
    }
  }
  __syncthreads();
  {
    const int k4 = (t & 15) * 4;
    const int r = t >> 4;
    unsigned short* d = dst + ((size_t)bz * N + n0) * K + k0;
#pragma unroll
    for (int i = 0; i < 4; ++i) {
      const int n = r + i * 16;
      ushort4 o;
      o.x = f2bf(tile[k4 + 0][n]); o.y = f2bf(tile[k4 + 1][n]);
      o.z = f2bf(tile[k4 + 2][n]); o.w = f2bf(tile[k4 + 3][n]);
      *(ushort4*)(d + (size_t)n * K + k4) = o;
    }
  }
}

__global__ __launch_bounds__(256) void prep_kernel(
    const float* __restrict__ x, unsigned short* __restrict__ xb,
    const float* __restrict__ W1, unsigned short* __restrict__ w1t,
    const float* __restrict__ W2, unsigned short* __restrict__ w2t,
    const int* __restrict__ view_ids, const int* __restrict__ visit_ids,
    const float* __restrict__ rview, const float* __restrict__ rvisit,
    int* __restrict__ top1, float* __restrict__ loss_out) {
  __shared__ float tile[64][65];
  __shared__ float probs[B_SZ][E_SZ];
  const int b = blockIdx.x;
  if (b < 8192) {
    const int i = b * 256 + threadIdx.x;
    const float4 v = reinterpret_cast<const float4*>(x)[i];
    ushort4 o;
    o.x = f2bf(v.x); o.y = f2bf(v.y); o.z = f2bf(v.z); o.w = f2bf(v.w);
    reinterpret_cast<ushort4*>(xb)[i] = o;
  } else if (b < 10240) {
    const int i = b - 8192;  // W1 grid (32, 8, 8)
    transpose_body(W1, w1t, D_SZ, DFF_SZ, i & 31, (i >> 5) & 7, i >> 8, tile);
  } else if (b < 12288) {
    const int i = b - 10240;  // W2 grid (8, 32, 8)
    transpose_body(W2, w2t, DFF_SZ, D_SZ, i & 7, (i >> 3) & 31, i >> 8, tile);
  } else {
    const int t = threadIdx.x;
    if (t < B_SZ) {
      const int vi = view_ids[t];
      const int si = visit_ids[t];
      float lg[E_SZ];
#pragma unroll
      for (int e = 0; e < E_SZ; ++e)
        lg[e] = rview[vi * E_SZ + e] + rvisit[si * E_SZ + e];
      int am = 0;
      float bm = lg[0];
#pragma unroll
      for (int e = 1; e < E_SZ; ++e)
        if (lg[e] > bm) { bm = lg[e]; am = e; }
      top1[t] = am;
      float s = 0.f;
#pragma unroll
      for (int e = 0; e < E_SZ; ++e) {
        const float p = expf(lg[e] - bm);
        probs[t][e] = p;
        s += p;
      }
      const float inv = 1.f / s;
#pragma unroll
      for (int e = 0; e < E_SZ; ++e) probs[t][e] *= inv;
    }
    __syncthreads();
    if (t == 0) {
      float loss = 0.f;
#pragma unroll
      for (int e = 0; e < E_SZ; ++e) {
        float ld = 0.f;
        for (int bb = 0; bb < B_SZ; ++bb) ld += probs[bb][e];
        ld *= (1.0f / B_SZ);
        loss -= ld * logf(ld);
      }
      *loss_out = loss;
    }
  }
}

// ---------------------------------------------------------------------------
// Grouped bf16 MFMA GEMM — TRIPLE-BUFFERED, 1 barrier + 1 counted vmcnt per
// K-tile (r5 had 8+1: five schedules all stuck at 23-27% MfmaUtil; the
// invariant was barrier count per unit work, not the interleave).
//
//   Tile 256x128, BK=64, 512 threads = 8 waves (4M x 2N), per-wave 64x64 out
//   = 4x4 frags of mfma_f32_16x16x32_bf16 (acc 64 f32/lane).
//   LDS: 3 bufs x (A 256x64 + B 128x64) bf16 = 144 KiB, 1 block/CU.
//   Per K-tile t: { stage(t+2) -> buf[(t+2)%3] (6 x global_load_lds) ;
//                   read 16 b128 frags from buf[t%3] ; 32 MFMA (setprio) ;
//                   vmcnt(6) ; s_barrier }
//   Hazards: WAR — buf[(t+2)%3] was last read at iter t-1, whose reads
//   retired before the t-1 barrier (their MFMAs consumed them) => safe with
//   ONE barrier. RAW — vmcnt(6) at end of t leaves only stage(t+2) in
//   flight => stage(t+1) landed before iter t+1 reads it. vmcnt(0) in tail.
//   Epilogue repacks acc through LDS (pad [64][68] f32) -> 16B coalesced
//   stores (was 128 scalar 2B stores/thread).
// ---------------------------------------------------------------------------
template <int NTILES, bool RELU, bool OUT_BF16>
__global__ __launch_bounds__(512, 2) void gemm_kernel(
    const unsigned short* __restrict__ A,
    const unsigned short* __restrict__ BT,
    const float* __restrict__ bias,
    const int* __restrict__ top1,
    void* __restrict__ Out,
    int N, int K) {
  constexpr int BUFB = (256 + 128) * 64 * 2;  // 48 KiB per buffer
  __shared__ __align__(16) unsigned short sm[3 * (256 + 128) * 64];  // 144 KiB

  const int t = threadIdx.x;
  const int lane = t & 63;
  const int wid = t >> 6;
  const int wm = wid >> 1;             // 0..3  (64-row band)
  const int wn = wid & 1;              // 0..1  (64-col band)
  const int lr = lane & 15, lg = lane >> 4;

  // block mapping + XCD-aware swizzle (grid % 8 == 0 in both instantiations)
  const int nwg = gridDim.x;
  const int bid = blockIdx.x;
  const int wg = (bid & 7) * (nwg >> 3) + (bid >> 3);
  const int mt = wg / NTILES;          // m-tile over B*L/256 = 64
  const int nt = wg % NTILES;
  const int n0 = nt * 128;
  const int bz = mt >> 2;              // 1024 rows per sample / 256
  const int e = top1[bz];

  // staging: thread t owns granule (row=t>>3, g=t&7); source granule is
  // pre-swizzled (g ^ row&7) so linear global_load_lds + swizzled ds_read match
  const size_t Kb = (size_t)K * 2;
  const int srow = t >> 3;                       // 0..63
  const int sgr = (t & 7) ^ (srow & 7);          // (row+64)&7 == row&7
  const char* aRow = (const char*)A + ((size_t)mt * 256 + srow) * Kb + sgr * 16;
  const char* bRow =
      (const char*)BT + ((size_t)e * N + n0 + srow) * Kb + sgr * 16;

  // stage one full K-tile (A: 4x64 rows, B: 2x64 rows) into buffer `buf`
  auto stage = [&](int buf, int kt) {
    char* dst = (char*)sm + (size_t)buf * BUFB + t * 16;
    const char* sa = aRow + (size_t)kt * 128;
#pragma unroll
    for (int c = 0; c < 4; ++c)
      async_cp16(dst + c * 8192, sa + (size_t)c * 64 * Kb);
    char* dstB = (char*)sm + (size_t)buf * BUFB + 32768 + t * 16;
    const char* sb = bRow + (size_t)kt * 128;
#pragma unroll
    for (int c = 0; c < 2; ++c)
      async_cp16(dstB + c * 8192, sb + (size_t)c * 64 * Kb);
  };

  f32x4 acc[4][4] = {};
  bf16x8 af[4][2], bg[4][2];
  const int nk = K >> 6;

  // prologue: tiles 0,1 staged; vmcnt(6) => tile 0 landed, tile 1 in flight
  stage(0, 0);
  stage(1, 1);
  asm volatile("s_waitcnt vmcnt(6)" ::: "memory");
  __builtin_amdgcn_s_barrier();
  asm volatile("" ::: "memory");

  int cur = 0;
  for (int kt = 0; kt < nk; ++kt) {
    const int s2 = cur ? cur - 1 : 2;            // (cur+2)%3
    if (kt + 2 < nk) stage(s2, kt + 2);
    const char* bufA = (const char*)sm + (size_t)cur * BUFB;
    const char* bufB = bufA + 32768;
#pragma unroll
    for (int mf = 0; mf < 4; ++mf) {
      const int row = wm * 64 + mf * 16 + lr;
#pragma unroll
      for (int ks = 0; ks < 2; ++ks)
        af[mf][ks] = *(const bf16x8*)(bufA + row * 128 +
                                      (((ks * 4 + lg) ^ (lr & 7)) << 4));
    }
#pragma unroll
    for (int nf = 0; nf < 4; ++nf) {
      const int row = wn * 64 + nf * 16 + lr;
#pragma unroll
      for (int ks = 0; ks < 2; ++ks)
        bg[nf][ks] = *(const bf16x8*)(bufB + row * 128 +
                                      (((ks * 4 + lg) ^ (lr & 7)) << 4));
    }
    __builtin_amdgcn_s_setprio(1);
#pragma unroll
    for (int ks = 0; ks < 2; ++ks)
#pragma unroll
      for (int mf = 0; mf < 4; ++mf)
#pragma unroll
        for (int nf = 0; nf < 4; ++nf)
          acc[mf][nf] = __builtin_amdgcn_mfma_f32_16x16x32_bf16(
              af[mf][ks], bg[nf][ks], acc[mf][nf], 0, 0, 0);
    __builtin_amdgcn_s_setprio(0);
    if (kt + 2 < nk) {
      asm volatile("s_waitcnt vmcnt(6)" ::: "memory");
    } else {
      asm volatile("s_waitcnt vmcnt(0)" ::: "memory");
    }
    __builtin_amdgcn_s_barrier();
    asm volatile("" ::: "memory");
    cur = (cur == 2) ? 0 : cur + 1;
  }

  // ---- epilogue: repack acc through LDS -> coalesced 16B/8B stores.
  // After final barrier no wave has pending LDS ops; sm is reusable.
  // Per-wave region: [64][68] f32 (68 => 16B-aligned rows, bank-rotated).
  float* wb = (float*)sm + (size_t)wid * (64 * 68);
  const float* bp = bias + (size_t)e * N + n0 + wn * 64;
  float bv[4];
#pragma unroll
  for (int j = 0; j < 4; ++j) bv[j] = bp[j * 16 + lr];
#pragma unroll
  for (int i = 0; i < 4; ++i)
#pragma unroll
    for (int j = 0; j < 4; ++j)
#pragma unroll
      for (int r = 0; r < 4; ++r) {
        const int row = i * 16 + lg * 4 + r;
        const int col = j * 16 + lr;
        float v = acc[i][j][r] + bv[j];
        if (RELU) v = fmaxf(v, 0.f);
        wb[row * 68 + col] = v;
      }
  // read back 4 rows per iteration (lg = row-subgroup, lr*4 = col)
  unsigned short* ho = (unsigned short*)Out;
  float* fo = (float*)Out;
  const size_t gr0 = (size_t)mt * 256 + wm * 64;
  const int gc0 = n0 + wn * 64 + lr * 4;
#pragma unroll
  for (int it = 0; it < 16; ++it) {
    const int row = it * 4 + lg;
    const float4 v = *(const float4*)&wb[row * 68 + lr * 4];
    const size_t o = (gr0 + row) * (size_t)N + gc0;
    if (OUT_BF16) {
      ushort4 u;
      u.x = f2bf(v.x); u.y = f2bf(v.y); u.z = f2bf(v.z); u.w = f2bf(v.w);
      *(ushort4*)&ho[o] = u;
    } else {
      *(float4*)&fo[o] = v;
    }
  }
}

// ---------------------------------------------------------------------------
// Launch
// ---------------------------------------------------------------------------
extern "C" void kernel_launch(void* const* d_in, const int* in_sizes, int n_in,
                              void* d_out, int out_size, void* d_ws,
                              size_t ws_size, hipStream_t stream) {
  const float* x = (const float*)d_in[0];
  const int* view_ids = (const int*)d_in[1];
  const int* visit_ids = (const int*)d_in[2];
  const float* rview = (const float*)d_in[3];
  const float* rvisit = (const float*)d_in[4];
  const float* W1 = (const float*)d_in[5];
  const float* b1 = (const float*)d_in[6];
  const float* W2 = (const float*)d_in[7];
  const float* b2 = (const float*)d_in[8];
  float* out = (float*)d_out;

  char* ws = (char*)d_ws;
  int* top1 = (int*)ws;                                               //    64 B
  unsigned short* x_bf = (unsigned short*)(ws + 256);                 // 16 MiB
  unsigned short* w1t = (unsigned short*)(ws + 256 + 16777216L);      // 16 MiB
  unsigned short* w2t = (unsigned short*)(ws + 256 + 2 * 16777216L);  // 16 MiB
  unsigned short* h_bf = (unsigned short*)(ws + 256 + 3 * 16777216L); // 64 MiB

  // 1 fused prep dispatch: cast + both transposes + router
  prep_kernel<<<12289, 256, 0, stream>>>(
      x, x_bf, W1, w1t, W2, w2t, view_ids, visit_ids, rview, rvisit, top1,
      out + (size_t)B_SZ * L_SZ * D_SZ);

  // GEMM1: h = relu(x @ W1[e] + b1[e]) -> bf16.  M=16384, N=2048, K=512.
  // 256x128 tiles: 64 x 16 = 1024 blocks (4 per CU), 8 K-tiles each.
  gemm_kernel<16, true, true><<<1024, 512, 0, stream>>>(
      x_bf, w1t, b1, top1, (void*)h_bf, DFF_SZ, D_SZ);
  // GEMM2: out = h @ W2[e] + b2[e] -> f32.  M=16384, N=512, K=2048.
  // 256x128 tiles: 64 x 4 = 256 blocks (1 per CU), 32 K-tiles each.
  gemm_kernel<4, false, false><<<256, 512, 0, stream>>>(
      h_bf, w2t, b2, top1, (void*)out, D_SZ, DFF_SZ);
}